// Round 2
// baseline (631.745 us; speedup 1.0000x reference)
//
#include <hip/hip_runtime.h>
#include <hip/hip_bf16.h>
#include <math.h>

#define B_ 64
#define C_ 384
#define M_ 1024
#define N_ 128
#define EPSV 1e-12f

// ---------------------------------------------------------------- phin
// phin_t[n][d] = scale * phi[d][n] / max(||phi[:,n]||, eps)
__global__ void k_phin(const float* __restrict__ phi, const float* __restrict__ scale,
                       float* __restrict__ phin_t) {
    int n = blockIdx.x;          // 128
    int t = threadIdx.x;         // 64
    float v[6];
    float ss = 0.f;
#pragma unroll
    for (int i = 0; i < 6; ++i) {
        int d = t + 64 * i;
        float u = phi[d * N_ + n];
        v[i] = u;
        ss += u * u;
    }
#pragma unroll
    for (int off = 32; off; off >>= 1) ss += __shfl_down(ss, off);
    ss = __shfl(ss, 0);
    float s = scale[0] / fmaxf(sqrtf(ss), EPSV);
#pragma unroll
    for (int i = 0; i < 6; ++i) {
        int d = t + 64 * i;
        phin_t[n * C_ + d] = v[i] * s;
    }
}

// ---------------------------------------------------------------- inv_norm
// inv_norm[b][m] = 1 / max(||x[b,:,m]||, eps)
__global__ void k_invnorm(const float* __restrict__ x, float* __restrict__ inv_norm) {
    int idx = blockIdx.x * 256 + threadIdx.x;   // B*M = 65536
    int b = idx >> 10, m = idx & (M_ - 1);
    const float* p = x + (size_t)b * C_ * M_ + m;
    float ss = 0.f;
#pragma unroll 4
    for (int c = 0; c < C_; ++c) { float u = p[(size_t)c * M_]; ss += u * u; }
    inv_norm[idx] = 1.0f / fmaxf(sqrtf(ss), EPSV);
}

// ---------------------------------------------------------------- logits GEMM
// L[b][n][m] = inv_norm[b][m] * sum_d phin_t[n][d] * x[b][d][m]
__global__ __launch_bounds__(256) void k_logits(const float* __restrict__ x,
                                                const float* __restrict__ phin_t,
                                                const float* __restrict__ inv_norm,
                                                float* __restrict__ L) {
    __shared__ float As[16][68];  // [k(d)][n]
    __shared__ float Bs[16][68];  // [k(d)][m]
    int b = blockIdx.z;
    int n0 = blockIdx.y * 64;
    int m0 = blockIdx.x * 64;
    int tid = threadIdx.x;
    int tm = tid & 15, tn = tid >> 4;
    float acc[4][4] = {};
    for (int k0 = 0; k0 < C_; k0 += 16) {
#pragma unroll
        for (int i = 0; i < 4; ++i) {
            int e = tid + 256 * i;
            int nr = e >> 4, dc = e & 15;
            As[dc][nr] = phin_t[(size_t)(n0 + nr) * C_ + k0 + dc];
        }
#pragma unroll
        for (int i = 0; i < 4; ++i) {
            int e = tid + 256 * i;
            int dr = e >> 6, mc = e & 63;
            Bs[dr][mc] = x[((size_t)b * C_ + k0 + dr) * M_ + m0 + mc];
        }
        __syncthreads();
#pragma unroll
        for (int kk = 0; kk < 16; ++kk) {
            float4 av = *reinterpret_cast<const float4*>(&As[kk][tn * 4]);
            float4 bv = *reinterpret_cast<const float4*>(&Bs[kk][tm * 4]);
            float a[4] = {av.x, av.y, av.z, av.w};
            float bb[4] = {bv.x, bv.y, bv.z, bv.w};
#pragma unroll
            for (int i = 0; i < 4; ++i)
#pragma unroll
                for (int j = 0; j < 4; ++j) acc[i][j] += a[i] * bb[j];
        }
        __syncthreads();
    }
#pragma unroll
    for (int j = 0; j < 4; ++j) {
        float inv = inv_norm[b * M_ + m0 + tm * 4 + j];
#pragma unroll
        for (int i = 0; i < 4; ++i)
            L[((size_t)b * N_ + n0 + tn * 4 + i) * M_ + m0 + tm * 4 + j] = acc[i][j] * inv;
    }
}

// ---------------------------------------------------------------- dispatch stats
// per (b,n): max over m, sum of exp over m
__global__ __launch_bounds__(256) void k_dstats(const float* __restrict__ L,
                                                float* __restrict__ dmax,
                                                float* __restrict__ dsum) {
    __shared__ float red[256];
    int bn = blockIdx.x;                 // B*N = 8192
    const float* row = L + (size_t)bn * M_;
    int t = threadIdx.x;
    float v[4];
    float mx = -3.4e38f;
#pragma unroll
    for (int i = 0; i < 4; ++i) { v[i] = row[t + 256 * i]; mx = fmaxf(mx, v[i]); }
    red[t] = mx;
    __syncthreads();
    for (int s = 128; s > 0; s >>= 1) {
        if (t < s) red[t] = fmaxf(red[t], red[t + s]);
        __syncthreads();
    }
    float MX = red[0];
    __syncthreads();
    float se = 0.f;
#pragma unroll
    for (int i = 0; i < 4; ++i) se += expf(v[i] - MX);
    red[t] = se;
    __syncthreads();
    for (int s = 128; s > 0; s >>= 1) {
        if (t < s) red[t] += red[t + s];
        __syncthreads();
    }
    if (t == 0) { dmax[bn] = MX; dsum[bn] = red[0]; }
}

// ---------------------------------------------------------------- combine stats
// per (b,m): max over n, sum of exp over n
__global__ void k_cstats(const float* __restrict__ L, float* __restrict__ cmax,
                         float* __restrict__ csum) {
    int idx = blockIdx.x * 256 + threadIdx.x;   // B*M
    int b = idx >> 10, m = idx & (M_ - 1);
    const float* p = L + (size_t)b * N_ * M_ + m;
    float mx = -3.4e38f;
#pragma unroll 4
    for (int n = 0; n < N_; ++n) mx = fmaxf(mx, p[(size_t)n * M_]);
    float s = 0.f;
#pragma unroll 4
    for (int n = 0; n < N_; ++n) s += expf(p[(size_t)n * M_] - mx);
    cmax[idx] = mx;
    csum[idx] = s;
}

// ---------------------------------------------------------------- xs GEMM
// xs[b][n][d] = (1/dsum) * sum_m exp(L[b][n][m]-dmax) * x[b][d][m]*inv_norm[b][m]
__global__ __launch_bounds__(256) void k_xs(const float* __restrict__ x,
                                            const float* __restrict__ L,
                                            const float* __restrict__ inv_norm,
                                            const float* __restrict__ dmax,
                                            const float* __restrict__ dsum,
                                            float* __restrict__ xs) {
    __shared__ float As[16][68];  // [k(m)][n]  exp weights
    __shared__ float Bs[16][68];  // [k(m)][d]  xn
    int b = blockIdx.z;
    int n0 = blockIdx.y * 64;
    int d0 = blockIdx.x * 64;
    int tid = threadIdx.x;
    int td = tid & 15, tn = tid >> 4;
    float acc[4][4] = {};
    for (int k0 = 0; k0 < M_; k0 += 16) {
#pragma unroll
        for (int i = 0; i < 4; ++i) {
            int e = tid + 256 * i;
            int nr = e >> 4, mc = e & 15;
            float lv = L[((size_t)b * N_ + n0 + nr) * M_ + k0 + mc];
            As[mc][nr] = expf(lv - dmax[b * N_ + n0 + nr]);
        }
#pragma unroll
        for (int i = 0; i < 4; ++i) {
            int e = tid + 256 * i;
            int dr = e >> 4, mc = e & 15;
            Bs[mc][dr] = x[((size_t)b * C_ + d0 + dr) * M_ + k0 + mc] *
                         inv_norm[b * M_ + k0 + mc];
        }
        __syncthreads();
#pragma unroll
        for (int kk = 0; kk < 16; ++kk) {
            float4 av = *reinterpret_cast<const float4*>(&As[kk][tn * 4]);
            float4 bv = *reinterpret_cast<const float4*>(&Bs[kk][td * 4]);
            float a[4] = {av.x, av.y, av.z, av.w};
            float bb[4] = {bv.x, bv.y, bv.z, bv.w};
#pragma unroll
            for (int i = 0; i < 4; ++i)
#pragma unroll
                for (int j = 0; j < 4; ++j) acc[i][j] += a[i] * bb[j];
        }
        __syncthreads();
    }
#pragma unroll
    for (int i = 0; i < 4; ++i) {
        float inv = 1.0f / dsum[b * N_ + n0 + tn * 4 + i];
#pragma unroll
        for (int j = 0; j < 4; ++j)
            xs[((size_t)b * N_ + n0 + tn * 4 + i) * C_ + d0 + td * 4 + j] = acc[i][j] * inv;
    }
}

// ---------------------------------------------------------------- ys GEMM (per expert)
// ys[b][n][o] = sum_d xs[b][n][d] * w_exp[n][o][d] + b_exp[n][o]
__global__ __launch_bounds__(256) void k_ys(const float* __restrict__ xs,
                                            const float* __restrict__ w_exp,
                                            const float* __restrict__ b_exp,
                                            float* __restrict__ ys) {
    __shared__ float As[16][68];  // [k(d)][b]
    __shared__ float Bs[16][68];  // [k(d)][o]
    int n = blockIdx.z;
    int o0 = blockIdx.x * 64;
    int tid = threadIdx.x;
    int to = tid & 15, tb = tid >> 4;
    float acc[4][4] = {};
    for (int k0 = 0; k0 < C_; k0 += 16) {
#pragma unroll
        for (int i = 0; i < 4; ++i) {
            int e = tid + 256 * i;
            int br = e >> 4, dc = e & 15;
            As[dc][br] = xs[((size_t)br * N_ + n) * C_ + k0 + dc];
        }
#pragma unroll
        for (int i = 0; i < 4; ++i) {
            int e = tid + 256 * i;
            int orr = e >> 4, dc = e & 15;
            Bs[dc][orr] = w_exp[((size_t)n * C_ + o0 + orr) * C_ + k0 + dc];
        }
        __syncthreads();
#pragma unroll
        for (int kk = 0; kk < 16; ++kk) {
            float4 av = *reinterpret_cast<const float4*>(&As[kk][tb * 4]);
            float4 bv = *reinterpret_cast<const float4*>(&Bs[kk][to * 4]);
            float a[4] = {av.x, av.y, av.z, av.w};
            float bb[4] = {bv.x, bv.y, bv.z, bv.w};
#pragma unroll
            for (int i = 0; i < 4; ++i)
#pragma unroll
                for (int j = 0; j < 4; ++j) acc[i][j] += a[i] * bb[j];
        }
        __syncthreads();
    }
#pragma unroll
    for (int i = 0; i < 4; ++i) {
        int bb_ = tb * 4 + i;
#pragma unroll
        for (int j = 0; j < 4; ++j) {
            int o = o0 + to * 4 + j;
            ys[((size_t)bb_ * N_ + n) * C_ + o] = acc[i][j] + b_exp[n * C_ + o];
        }
    }
}

// ---------------------------------------------------------------- y GEMM
// out[b][d][m] = (sum_n ys[b][n][d] * exp(L[b][n][m]-cmax[b][m])) / csum[b][m]
__global__ __launch_bounds__(256) void k_y(const float* __restrict__ ys,
                                           const float* __restrict__ L,
                                           const float* __restrict__ cmax,
                                           const float* __restrict__ csum,
                                           float* __restrict__ out) {
    __shared__ float As[16][68];  // [k(n)][d]
    __shared__ float Bs[16][68];  // [k(n)][m]
    int b = blockIdx.z;
    int d0 = blockIdx.y * 64;
    int m0 = blockIdx.x * 64;
    int tid = threadIdx.x;
    int tm = tid & 15, td = tid >> 4;
    float acc[4][4] = {};
    for (int k0 = 0; k0 < N_; k0 += 16) {
#pragma unroll
        for (int i = 0; i < 4; ++i) {
            int e = tid + 256 * i;
            int nr = e >> 6, dc = e & 63;
            As[nr][dc] = ys[((size_t)b * N_ + k0 + nr) * C_ + d0 + dc];
        }
#pragma unroll
        for (int i = 0; i < 4; ++i) {
            int e = tid + 256 * i;
            int nr = e >> 6, mc = e & 63;
            float lv = L[((size_t)b * N_ + k0 + nr) * M_ + m0 + mc];
            Bs[nr][mc] = expf(lv - cmax[b * M_ + m0 + mc]);
        }
        __syncthreads();
#pragma unroll
        for (int kk = 0; kk < 16; ++kk) {
            float4 av = *reinterpret_cast<const float4*>(&As[kk][td * 4]);
            float4 bv = *reinterpret_cast<const float4*>(&Bs[kk][tm * 4]);
            float a[4] = {av.x, av.y, av.z, av.w};
            float bb[4] = {bv.x, bv.y, bv.z, bv.w};
#pragma unroll
            for (int i = 0; i < 4; ++i)
#pragma unroll
                for (int j = 0; j < 4; ++j) acc[i][j] += a[i] * bb[j];
        }
        __syncthreads();
    }
#pragma unroll
    for (int j = 0; j < 4; ++j) {
        float inv = 1.0f / csum[b * M_ + m0 + tm * 4 + j];
#pragma unroll
        for (int i = 0; i < 4; ++i)
            out[((size_t)b * C_ + d0 + td * 4 + i) * M_ + m0 + tm * 4 + j] = acc[i][j] * inv;
    }
}

extern "C" void kernel_launch(void* const* d_in, const int* in_sizes, int n_in,
                              void* d_out, int out_size, void* d_ws, size_t ws_size,
                              hipStream_t stream) {
    const float* x     = (const float*)d_in[0];  // [64][384][1024]
    const float* phi   = (const float*)d_in[1];  // [384][128]
    const float* scale = (const float*)d_in[2];  // [1]
    const float* w_exp = (const float*)d_in[3];  // [128][384][384]
    const float* b_exp = (const float*)d_in[4];  // [128][384]
    float* out = (float*)d_out;                  // [64][384][1024]

    float* w = (float*)d_ws;
    float* phin_t   = w;             // 49152   [128][384]
    float* inv_norm = w + 49152;     // 65536   [64][1024]
    float* dmax     = w + 114688;    // 8192    [64][128]
    float* dsum     = w + 122880;    // 8192
    float* cmax     = w + 131072;    // 65536   [64][1024]
    float* csum     = w + 196608;    // 65536
    float* xs       = w + 262144;    // 3145728 [64][128][384]
    float* ys       = w + 3407872;   // 3145728 [64][128][384]
    float* L        = w + 6553600;   // 8388608 [64][128][1024]
    // total 14,942,208 floats = 59.8 MB of d_ws

    k_phin<<<dim3(128), dim3(64), 0, stream>>>(phi, scale, phin_t);
    k_invnorm<<<dim3(256), dim3(256), 0, stream>>>(x, inv_norm);
    k_logits<<<dim3(16, 2, 64), dim3(256), 0, stream>>>(x, phin_t, inv_norm, L);
    k_dstats<<<dim3(8192), dim3(256), 0, stream>>>(L, dmax, dsum);
    k_cstats<<<dim3(256), dim3(256), 0, stream>>>(L, cmax, csum);
    k_xs<<<dim3(6, 2, 64), dim3(256), 0, stream>>>(x, L, inv_norm, dmax, dsum, xs);
    k_ys<<<dim3(6, 1, 128), dim3(256), 0, stream>>>(xs, w_exp, b_exp, ys);
    k_y<<<dim3(16, 6, 64), dim3(256), 0, stream>>>(ys, L, cmax, csum, out);
}

// Round 3
// 466.923 us; speedup vs baseline: 1.3530x; 1.3530x over previous
//
#include <hip/hip_runtime.h>
#include <hip/hip_bf16.h>
#include <math.h>

#define B_ 64
#define C_ 384
#define M_ 1024
#define N_ 128
#define EPSV 1e-12f

typedef __attribute__((ext_vector_type(8))) short bf16x8;
typedef __attribute__((ext_vector_type(4))) float f32x4;

__device__ __forceinline__ short f2b(float f) {
    unsigned u = __float_as_uint(f);
    unsigned r = (u + 0x7FFFu + ((u >> 16) & 1u)) >> 16;
    return (short)r;
}

// ---- swizzled global->LDS staging of an R x 32 bf16 tile (row-major, ld elems)
// LDS layout: chunk(row,kq) at row*4 + (kq ^ ((row>>1)&3))  [16B chunks]
template <int R>
__device__ __forceinline__ void stage32(const short* gbase, size_t ld, short* lds, int tid) {
    int w = tid >> 6, l = tid & 63;
#pragma unroll
    for (int q = 0; q < (R >> 6); ++q) {
        int c = ((q << 2) + w) * 64 + l;
        int row = c >> 2;
        int kq = (c & 3) ^ ((row >> 1) & 3);
        const short* src = gbase + (size_t)row * ld + (kq << 3);
        short* dst = lds + (((q << 2) + w) << 9);  // wave-uniform 1KB slabs
        __builtin_amdgcn_global_load_lds((const __attribute__((address_space(1))) void*)src,
                                         (__attribute__((address_space(3))) void*)dst, 16, 0, 0);
    }
}

__device__ __forceinline__ bf16x8 fragLd(const short* lds, int row, int g) {
    int kq = g ^ ((row >> 1) & 3);
    return *reinterpret_cast<const bf16x8*>(lds + row * 32 + (kq << 3));
}

#define MFMA16(a, b, c) __builtin_amdgcn_mfma_f32_16x16x32_bf16(a, b, c, 0, 0, 0)

// ---------------------------------------------------------------- phin (bf16 out)
__global__ void k_phin(const float* __restrict__ phi, const float* __restrict__ scale,
                       short* __restrict__ phin_bf) {
    int n = blockIdx.x, t = threadIdx.x;
    float v[6];
    float ss = 0.f;
#pragma unroll
    for (int i = 0; i < 6; ++i) {
        int d = t + 64 * i;
        float u = phi[d * N_ + n];
        v[i] = u; ss += u * u;
    }
#pragma unroll
    for (int off = 32; off; off >>= 1) ss += __shfl_down(ss, off);
    ss = __shfl(ss, 0);
    float s = scale[0] / fmaxf(sqrtf(ss), EPSV);
#pragma unroll
    for (int i = 0; i < 6; ++i) phin_bf[n * C_ + t + 64 * i] = f2b(v[i] * s);
}

// ---------------------------------------------------------------- w_exp -> bf16
__global__ void k_cvt(const float* __restrict__ in, short* __restrict__ out, int n8) {
    for (int i = blockIdx.x * 256 + threadIdx.x; i < n8; i += gridDim.x * 256) {
        float4 a = reinterpret_cast<const float4*>(in)[2 * i];
        float4 b = reinterpret_cast<const float4*>(in)[2 * i + 1];
        bf16x8 r;
        r[0] = f2b(a.x); r[1] = f2b(a.y); r[2] = f2b(a.z); r[3] = f2b(a.w);
        r[4] = f2b(b.x); r[5] = f2b(b.y); r[6] = f2b(b.z); r[7] = f2b(b.w);
        reinterpret_cast<bf16x8*>(out)[i] = r;
    }
}

// ---------------------------------------------------------------- xn: x -> bf16 normalized [b][d][m]
__global__ void k_xn(const float* __restrict__ x, short* __restrict__ xdm) {
    int b = blockIdx.y;
    int m = blockIdx.x * 256 + threadIdx.x;
    const float* p = x + (size_t)b * C_ * M_ + m;
    float ss = 0.f;
#pragma unroll 4
    for (int c = 0; c < C_; ++c) { float u = p[(size_t)c * M_]; ss += u * u; }
    float inv = 1.0f / fmaxf(sqrtf(ss), EPSV);
    short* q = xdm + (size_t)b * C_ * M_ + m;
#pragma unroll 4
    for (int c = 0; c < C_; ++c) q[(size_t)c * M_] = f2b(p[(size_t)c * M_] * inv);
}

// ---------------------------------------------------------------- bf16 tile transpose [b][RI][CI] -> [b][CI][RI]
__global__ __launch_bounds__(256) void k_tr(const short* __restrict__ in, short* __restrict__ out,
                                            int RI, int CI) {
    __shared__ __align__(16) short t[64][68];
    int b = blockIdx.z, c0 = blockIdx.x * 64, r0 = blockIdx.y * 64;
    int tid = threadIdx.x;
    int cq = (tid & 15) * 4, rp = tid >> 4;
    const size_t ibase = (size_t)b * RI * CI;
#pragma unroll
    for (int p = 0; p < 4; ++p) {
        int r = r0 + p * 16 + rp;
        short4 v = *reinterpret_cast<const short4*>(in + ibase + (size_t)r * CI + c0 + cq);
        t[p * 16 + rp][cq + 0] = v.x; t[p * 16 + rp][cq + 1] = v.y;
        t[p * 16 + rp][cq + 2] = v.z; t[p * 16 + rp][cq + 3] = v.w;
    }
    __syncthreads();
    const size_t obase = (size_t)b * CI * RI;
#pragma unroll
    for (int p = 0; p < 4; ++p) {
        int c = c0 + p * 16 + rp;
        short4 v;
        v.x = t[cq + 0][p * 16 + rp]; v.y = t[cq + 1][p * 16 + rp];
        v.z = t[cq + 2][p * 16 + rp]; v.w = t[cq + 3][p * 16 + rp];
        *reinterpret_cast<short4*>(out + obase + (size_t)c * RI + r0 + cq) = v;
    }
}

// ---------------------------------------------------------------- G1: L[b][n][m] fp32 (128x128 tile)
__global__ __launch_bounds__(256) void k_glogits(const short* __restrict__ phin_bf,
                                                 const short* __restrict__ xmd,
                                                 float* __restrict__ L) {
    __shared__ __align__(16) short lA[4096];
    __shared__ __align__(16) short lB[4096];
    int tid = threadIdx.x, b = blockIdx.z, m0 = blockIdx.x * 128;
    int w = tid >> 6, wr = w >> 1, wc = w & 1, l = tid & 63, g = l >> 4, lr = l & 15;
    f32x4 acc[4][4];
#pragma unroll
    for (int i = 0; i < 4; ++i)
#pragma unroll
        for (int j = 0; j < 4; ++j) acc[i][j] = (f32x4)(0.f);
    for (int k0 = 0; k0 < C_; k0 += 32) {
        stage32<128>(phin_bf + k0, C_, lA, tid);
        stage32<128>(xmd + ((size_t)(b * M_ + m0)) * C_ + k0, C_, lB, tid);
        __syncthreads();
        bf16x8 af[4], bf[4];
#pragma unroll
        for (int i = 0; i < 4; ++i) af[i] = fragLd(lA, wr * 64 + i * 16 + lr, g);
#pragma unroll
        for (int j = 0; j < 4; ++j) bf[j] = fragLd(lB, wc * 64 + j * 16 + lr, g);
#pragma unroll
        for (int i = 0; i < 4; ++i)
#pragma unroll
            for (int j = 0; j < 4; ++j) acc[i][j] = MFMA16(af[i], bf[j], acc[i][j]);
        __syncthreads();
    }
#pragma unroll
    for (int i = 0; i < 4; ++i)
#pragma unroll
        for (int j = 0; j < 4; ++j)
#pragma unroll
            for (int rr = 0; rr < 4; ++rr) {
                int n = wr * 64 + i * 16 + g * 4 + rr;
                int m = m0 + wc * 64 + j * 16 + lr;
                L[((size_t)b * N_ + n) * M_ + m] = acc[i][j][rr];
            }
}

// ---------------------------------------------------------------- dispatch stats
__global__ __launch_bounds__(256) void k_dstats(const float* __restrict__ L,
                                                float* __restrict__ dmax, float* __restrict__ dsum) {
    __shared__ float red[256];
    int bn = blockIdx.x;
    const float* row = L + (size_t)bn * M_;
    int t = threadIdx.x;
    float v[4];
    float mx = -3.4e38f;
#pragma unroll
    for (int i = 0; i < 4; ++i) { v[i] = row[t + 256 * i]; mx = fmaxf(mx, v[i]); }
    red[t] = mx; __syncthreads();
    for (int s = 128; s > 0; s >>= 1) { if (t < s) red[t] = fmaxf(red[t], red[t + s]); __syncthreads(); }
    float MX = red[0]; __syncthreads();
    float se = 0.f;
#pragma unroll
    for (int i = 0; i < 4; ++i) se += expf(v[i] - MX);
    red[t] = se; __syncthreads();
    for (int s = 128; s > 0; s >>= 1) { if (t < s) red[t] += red[t + s]; __syncthreads(); }
    if (t == 0) { dmax[bn] = MX; dsum[bn] = red[0]; }
}

// ---------------------------------------------------------------- combine stats
__global__ void k_cstats(const float* __restrict__ L, float* __restrict__ cmax,
                         float* __restrict__ csum) {
    int idx = blockIdx.x * 256 + threadIdx.x;
    int b = idx >> 10, m = idx & (M_ - 1);
    const float* p = L + (size_t)b * N_ * M_ + m;
    float mx = -3.4e38f;
#pragma unroll 4
    for (int n = 0; n < N_; ++n) mx = fmaxf(mx, p[(size_t)n * M_]);
    float s = 0.f;
#pragma unroll 4
    for (int n = 0; n < N_; ++n) s += expf(p[(size_t)n * M_] - mx);
    cmax[idx] = mx; csum[idx] = s;
}

// ---------------------------------------------------------------- weights: D bf16 [b][n][m], C^T bf16 [b][m][n]
__global__ __launch_bounds__(256) void k_weights(const float* __restrict__ L,
                                                 const float* __restrict__ dmax, const float* __restrict__ dsum,
                                                 const float* __restrict__ cmax, const float* __restrict__ csum,
                                                 short* __restrict__ Dbf, short* __restrict__ Ct) {
    __shared__ __align__(16) short t[64][68];
    int b = blockIdx.z, n0 = blockIdx.y * 64, m0 = blockIdx.x * 64;
    int tid = threadIdx.x;
    int col = tid & 63, rp = tid >> 6;
    float cm = cmax[b * M_ + m0 + col];
    float rcs = 1.0f / csum[b * M_ + m0 + col];
#pragma unroll 4
    for (int rr = 0; rr < 16; ++rr) {
        int row = rr * 4 + rp;
        int n = n0 + row;
        float lv = L[((size_t)b * N_ + n) * M_ + m0 + col];
        float dv = expf(lv - dmax[b * N_ + n]) * (1.0f / dsum[b * N_ + n]);
        Dbf[((size_t)b * N_ + n) * M_ + m0 + col] = f2b(dv);
        t[row][col] = f2b(expf(lv - cm) * rcs);
    }
    __syncthreads();
    int cq = (tid & 15) * 4, rp2 = tid >> 4;
#pragma unroll
    for (int p = 0; p < 4; ++p) {
        int m = m0 + p * 16 + rp2;
        short4 v;
        v.x = t[cq + 0][p * 16 + rp2]; v.y = t[cq + 1][p * 16 + rp2];
        v.z = t[cq + 2][p * 16 + rp2]; v.w = t[cq + 3][p * 16 + rp2];
        *reinterpret_cast<short4*>(Ct + ((size_t)b * M_ + m) * N_ + n0 + cq) = v;
    }
}

// ---------------------------------------------------------------- G2: xs_bf[b][n][d] (64x128 tile, K=M)
__global__ __launch_bounds__(256) void k_gxs(const short* __restrict__ Dbf,
                                             const short* __restrict__ xdm,
                                             short* __restrict__ xs_bf) {
    __shared__ __align__(16) short lA[2048];
    __shared__ __align__(16) short lB[4096];
    int tid = threadIdx.x, b = blockIdx.z, n0 = blockIdx.y * 64, d0 = blockIdx.x * 128;
    int w = tid >> 6, l = tid & 63, g = l >> 4, lr = l & 15;
    f32x4 acc[4][2];
#pragma unroll
    for (int i = 0; i < 4; ++i)
#pragma unroll
        for (int j = 0; j < 2; ++j) acc[i][j] = (f32x4)(0.f);
    for (int k0 = 0; k0 < M_; k0 += 32) {
        stage32<64>(Dbf + ((size_t)(b * N_ + n0)) * M_ + k0, M_, lA, tid);
        stage32<128>(xdm + ((size_t)(b * C_ + d0)) * M_ + k0, M_, lB, tid);
        __syncthreads();
        bf16x8 af[4], bf[2];
#pragma unroll
        for (int i = 0; i < 4; ++i) af[i] = fragLd(lA, i * 16 + lr, g);
#pragma unroll
        for (int j = 0; j < 2; ++j) bf[j] = fragLd(lB, w * 32 + j * 16 + lr, g);
#pragma unroll
        for (int i = 0; i < 4; ++i)
#pragma unroll
            for (int j = 0; j < 2; ++j) acc[i][j] = MFMA16(af[i], bf[j], acc[i][j]);
        __syncthreads();
    }
#pragma unroll
    for (int i = 0; i < 4; ++i)
#pragma unroll
        for (int j = 0; j < 2; ++j)
#pragma unroll
            for (int rr = 0; rr < 4; ++rr) {
                int n = n0 + i * 16 + g * 4 + rr;
                int d = d0 + w * 32 + j * 16 + lr;
                xs_bf[((size_t)b * N_ + n) * C_ + d] = f2b(acc[i][j][rr]);
            }
}

// ---------------------------------------------------------------- G3: ys_bf[b][n][o] per expert (64x128 tile, K=C)
__global__ __launch_bounds__(256) void k_gys(const short* __restrict__ xs_bf,
                                             const short* __restrict__ wbf,
                                             const float* __restrict__ b_exp,
                                             short* __restrict__ ys_bf) {
    __shared__ __align__(16) short lA[2048];
    __shared__ __align__(16) short lB[4096];
    int tid = threadIdx.x, n = blockIdx.y, o0 = blockIdx.x * 128;
    int w = tid >> 6, l = tid & 63, g = l >> 4, lr = l & 15;
    f32x4 acc[4][2];
#pragma unroll
    for (int i = 0; i < 4; ++i)
#pragma unroll
        for (int j = 0; j < 2; ++j) acc[i][j] = (f32x4)(0.f);
    for (int k0 = 0; k0 < C_; k0 += 32) {
        stage32<64>(xs_bf + (size_t)n * C_ + k0, (size_t)N_ * C_, lA, tid);
        stage32<128>(wbf + ((size_t)n * C_ + o0) * C_ + k0, C_, lB, tid);
        __syncthreads();
        bf16x8 af[4], bf[2];
#pragma unroll
        for (int i = 0; i < 4; ++i) af[i] = fragLd(lA, i * 16 + lr, g);
#pragma unroll
        for (int j = 0; j < 2; ++j) bf[j] = fragLd(lB, w * 32 + j * 16 + lr, g);
#pragma unroll
        for (int i = 0; i < 4; ++i)
#pragma unroll
            for (int j = 0; j < 2; ++j) acc[i][j] = MFMA16(af[i], bf[j], acc[i][j]);
        __syncthreads();
    }
#pragma unroll
    for (int i = 0; i < 4; ++i)
#pragma unroll
        for (int j = 0; j < 2; ++j)
#pragma unroll
            for (int rr = 0; rr < 4; ++rr) {
                int bb = i * 16 + g * 4 + rr;
                int o = o0 + w * 32 + j * 16 + lr;
                float v = acc[i][j][rr] + b_exp[n * C_ + o];
                ys_bf[((size_t)bb * N_ + n) * C_ + o] = f2b(v);
            }
}

// ---------------------------------------------------------------- G4: out[b][d][m] fp32 (128x128 tile, K=N)
__global__ __launch_bounds__(256) void k_gy(const short* __restrict__ ysT,
                                            const short* __restrict__ Ct,
                                            float* __restrict__ out) {
    __shared__ __align__(16) short lA[4096];
    __shared__ __align__(16) short lB[4096];
    int tid = threadIdx.x, b = blockIdx.z, d0 = blockIdx.y * 128, m0 = blockIdx.x * 128;
    int w = tid >> 6, wr = w >> 1, wc = w & 1, l = tid & 63, g = l >> 4, lr = l & 15;
    f32x4 acc[4][4];
#pragma unroll
    for (int i = 0; i < 4; ++i)
#pragma unroll
        for (int j = 0; j < 4; ++j) acc[i][j] = (f32x4)(0.f);
    for (int k0 = 0; k0 < N_; k0 += 32) {
        stage32<128>(ysT + ((size_t)(b * C_ + d0)) * N_ + k0, N_, lA, tid);
        stage32<128>(Ct + ((size_t)(b * M_ + m0)) * N_ + k0, N_, lB, tid);
        __syncthreads();
        bf16x8 af[4], bf[4];
#pragma unroll
        for (int i = 0; i < 4; ++i) af[i] = fragLd(lA, wr * 64 + i * 16 + lr, g);
#pragma unroll
        for (int j = 0; j < 4; ++j) bf[j] = fragLd(lB, wc * 64 + j * 16 + lr, g);
#pragma unroll
        for (int i = 0; i < 4; ++i)
#pragma unroll
            for (int j = 0; j < 4; ++j) acc[i][j] = MFMA16(af[i], bf[j], acc[i][j]);
        __syncthreads();
    }
#pragma unroll
    for (int i = 0; i < 4; ++i)
#pragma unroll
        for (int j = 0; j < 4; ++j)
#pragma unroll
            for (int rr = 0; rr < 4; ++rr) {
                int d = d0 + wr * 64 + i * 16 + g * 4 + rr;
                int m = m0 + wc * 64 + j * 16 + lr;
                out[((size_t)b * C_ + d) * M_ + m] = acc[i][j][rr];
            }
}

extern "C" void kernel_launch(void* const* d_in, const int* in_sizes, int n_in,
                              void* d_out, int out_size, void* d_ws, size_t ws_size,
                              hipStream_t stream) {
    const float* x     = (const float*)d_in[0];
    const float* phi   = (const float*)d_in[1];
    const float* scale = (const float*)d_in[2];
    const float* w_exp = (const float*)d_in[3];
    const float* b_exp = (const float*)d_in[4];
    float* out = (float*)d_out;

    char* w = (char*)d_ws;
    float* L     = (float*)(w + 0);                 // 33,554,432 B
    float* dmax  = (float*)(w + 33554432);          // 32,768
    float* dsum  = (float*)(w + 33587200);          // 32,768
    float* cmax  = (float*)(w + 33619968);          // 262,144
    float* csum  = (float*)(w + 33882112);          // 262,144
    short* phin  = (short*)(w + 34144256);          // 98,304
    short* wbf   = (short*)(w + 34242560);          // 37,748,736
    short* xdm   = (short*)(w + 71991296);          // 50,331,648  xn bf16 [b][d][m]
    short* xmd   = (short*)(w + 122322944);         // 50,331,648  xn bf16 [b][m][d] (dead after G1)
    short* Dbf   = (short*)(w + 172654592);         // 16,777,216
    short* Ct    = (short*)(w + 189431808);         // 16,777,216  (end: 206,209,024)
    // alias into xmd region (xmd dead after k_glogits; these written after):
    short* xs_bf = xmd;                             // 6,291,456
    short* ys_bf = xmd + 3145728;                   // 6,291,456
    short* ysT   = xmd + 6291456;                   // 6,291,456

    if (ws_size < 206209024) return;  // clean failure instead of OOB

    k_phin<<<dim3(128), dim3(64), 0, stream>>>(phi, scale, phin);
    k_cvt<<<dim3(2048), dim3(256), 0, stream>>>(w_exp, wbf, N_ * C_ * C_ / 8);
    k_xn<<<dim3(4, 64), dim3(256), 0, stream>>>(x, xdm);
    k_tr<<<dim3(16, 6, 64), dim3(256), 0, stream>>>(xdm, xmd, C_, M_);
    k_glogits<<<dim3(8, 1, 64), dim3(256), 0, stream>>>(phin, xmd, L);
    k_dstats<<<dim3(8192), dim3(256), 0, stream>>>(L, dmax, dsum);
    k_cstats<<<dim3(256), dim3(256), 0, stream>>>(L, cmax, csum);
    k_weights<<<dim3(16, 2, 64), dim3(256), 0, stream>>>(L, dmax, dsum, cmax, csum, Dbf, Ct);
    k_gxs<<<dim3(3, 2, 64), dim3(256), 0, stream>>>(Dbf, xdm, xs_bf);
    k_gys<<<dim3(3, 128), dim3(256), 0, stream>>>(xs_bf, wbf, b_exp, ys_bf);
    k_tr<<<dim3(6, 2, 64), dim3(256), 0, stream>>>(ys_bf, ysT, N_, C_);
    k_gy<<<dim3(8, 3, 64), dim3(256), 0, stream>>>(ysT, Ct, out);
}

// Round 4
// 395.418 us; speedup vs baseline: 1.5977x; 1.1808x over previous
//
#include <hip/hip_runtime.h>
#include <hip/hip_bf16.h>
#include <math.h>

#define B_ 64
#define C_ 384
#define M_ 1024
#define N_ 128
#define EPSV 1e-12f

typedef __attribute__((ext_vector_type(8))) short bf16x8;
typedef __attribute__((ext_vector_type(4))) float f32x4;

__device__ __forceinline__ short f2b(float f) {
    unsigned u = __float_as_uint(f);
    unsigned r = (u + 0x7FFFu + ((u >> 16) & 1u)) >> 16;
    return (short)r;
}

// ---- swizzled global->LDS staging of an R x 32 bf16 tile (row-major, ld elems)
// LDS layout: 16B chunk slot q' at row*4+q' holds global chunk q'^((row>>1)&3)
template <int R>
__device__ __forceinline__ void stage32(const short* gbase, size_t ld, short* lds, int tid) {
    int w = tid >> 6, l = tid & 63;
#pragma unroll
    for (int q = 0; q < (R >> 6); ++q) {
        int c = ((q << 2) + w) * 64 + l;
        int row = c >> 2;
        int kq = (c & 3) ^ ((row >> 1) & 3);
        const short* src = gbase + (size_t)row * ld + (kq << 3);
        short* dst = lds + (((q << 2) + w) << 9);  // wave-uniform 1KB slabs
        __builtin_amdgcn_global_load_lds((const __attribute__((address_space(1))) void*)src,
                                         (__attribute__((address_space(3))) void*)dst, 16, 0, 0);
    }
}

__device__ __forceinline__ bf16x8 fragLd(const short* lds, int row, int g) {
    int kq = g ^ ((row >> 1) & 3);
    return *reinterpret_cast<const bf16x8*>(lds + row * 32 + (kq << 3));
}

#define MFMA16(a, b, c) __builtin_amdgcn_mfma_f32_16x16x32_bf16(a, b, c, 0, 0, 0)

// ---------------------------------------------------------------- phin (bf16 out)
__global__ void k_phin(const float* __restrict__ phi, const float* __restrict__ scale,
                       short* __restrict__ phin_bf) {
    int n = blockIdx.x, t = threadIdx.x;
    float v[6];
    float ss = 0.f;
#pragma unroll
    for (int i = 0; i < 6; ++i) {
        int d = t + 64 * i;
        float u = phi[d * N_ + n];
        v[i] = u; ss += u * u;
    }
#pragma unroll
    for (int off = 32; off; off >>= 1) ss += __shfl_down(ss, off);
    ss = __shfl(ss, 0);
    float s = scale[0] / fmaxf(sqrtf(ss), EPSV);
#pragma unroll
    for (int i = 0; i < 6; ++i) phin_bf[n * C_ + t + 64 * i] = f2b(v[i] * s);
}

// ---------------------------------------------------------------- fused xn + dual-layout write
// Per (b, 64-m tile): phase1 sum-of-squares (float4 loads), phase2 re-read,
// write xdm[b][d][m] (bf16) coalesced and xmd[b][m][d] via LDS transpose.
__global__ __launch_bounds__(256) void k_xnt(const float* __restrict__ x,
                                             short* __restrict__ xdm,
                                             short* __restrict__ xmd) {
    __shared__ float ssred[16][64];
    __shared__ float invs[64];
    __shared__ __align__(16) short tr[64][68];
    int b = blockIdx.y, m0 = blockIdx.x * 64;
    int tid = threadIdx.x;
    int mq = tid & 15, cp = tid >> 4;           // mq: m-quad (4 m's), cp: c-part / c-row
    const float* xb = x + (size_t)b * C_ * M_ + m0;
    // ---- phase 1: per-m sum of squares
    float ss0 = 0.f, ss1 = 0.f, ss2 = 0.f, ss3 = 0.f;
#pragma unroll
    for (int i = 0; i < 24; ++i) {
        int c = cp * 24 + i;
        float4 v = *reinterpret_cast<const float4*>(xb + (size_t)c * M_ + mq * 4);
        ss0 += v.x * v.x; ss1 += v.y * v.y; ss2 += v.z * v.z; ss3 += v.w * v.w;
    }
    ssred[cp][mq * 4 + 0] = ss0; ssred[cp][mq * 4 + 1] = ss1;
    ssred[cp][mq * 4 + 2] = ss2; ssred[cp][mq * 4 + 3] = ss3;
    __syncthreads();
    if (tid < 64) {
        float s = 0.f;
#pragma unroll
        for (int k = 0; k < 16; ++k) s += ssred[k][tid];
        invs[tid] = 1.0f / fmaxf(sqrtf(s), EPSV);
    }
    __syncthreads();
    float inv0 = invs[mq * 4 + 0], inv1 = invs[mq * 4 + 1];
    float inv2 = invs[mq * 4 + 2], inv3 = invs[mq * 4 + 3];
    // ---- phase 2: six 64-c panels
#pragma unroll
    for (int p = 0; p < 6; ++p) {
#pragma unroll
        for (int i = 0; i < 4; ++i) {
            int cl = i * 16 + cp;              // local c in [0,64)
            int c = p * 64 + cl;
            float4 v = *reinterpret_cast<const float4*>(xb + (size_t)c * M_ + mq * 4);
            short4 o;
            o.x = f2b(v.x * inv0); o.y = f2b(v.y * inv1);
            o.z = f2b(v.z * inv2); o.w = f2b(v.w * inv3);
            *reinterpret_cast<short4*>(xdm + ((size_t)b * C_ + c) * M_ + m0 + mq * 4) = o;
            *reinterpret_cast<short4*>(&tr[cl][mq * 4]) = o;
        }
        __syncthreads();
#pragma unroll
        for (int q = 0; q < 4; ++q) {
            int m = q * 16 + cp;               // cp doubles as m-row index here
            short4 v;
            v.x = tr[mq * 4 + 0][m]; v.y = tr[mq * 4 + 1][m];
            v.z = tr[mq * 4 + 2][m]; v.w = tr[mq * 4 + 3][m];
            *reinterpret_cast<short4*>(xmd + ((size_t)b * M_ + m0 + m) * C_ + p * 64 + mq * 4) = v;
        }
        __syncthreads();
    }
}

// ---------------------------------------------------------------- bf16 tile transpose [b][RI][CI] -> [b][CI][RI]
__global__ __launch_bounds__(256) void k_tr(const short* __restrict__ in, short* __restrict__ out,
                                            int RI, int CI) {
    __shared__ __align__(16) short t[64][68];
    int b = blockIdx.z, c0 = blockIdx.x * 64, r0 = blockIdx.y * 64;
    int tid = threadIdx.x;
    int cq = (tid & 15) * 4, rp = tid >> 4;
    const size_t ibase = (size_t)b * RI * CI;
#pragma unroll
    for (int p = 0; p < 4; ++p) {
        int r = r0 + p * 16 + rp;
        short4 v = *reinterpret_cast<const short4*>(in + ibase + (size_t)r * CI + c0 + cq);
        t[p * 16 + rp][cq + 0] = v.x; t[p * 16 + rp][cq + 1] = v.y;
        t[p * 16 + rp][cq + 2] = v.z; t[p * 16 + rp][cq + 3] = v.w;
    }
    __syncthreads();
    const size_t obase = (size_t)b * CI * RI;
#pragma unroll
    for (int p = 0; p < 4; ++p) {
        int c = c0 + p * 16 + rp;
        short4 v;
        v.x = t[cq + 0][p * 16 + rp]; v.y = t[cq + 1][p * 16 + rp];
        v.z = t[cq + 2][p * 16 + rp]; v.w = t[cq + 3][p * 16 + rp];
        *reinterpret_cast<short4*>(out + obase + (size_t)c * RI + r0 + cq) = v;
    }
}

// ---------------------------------------------------------------- G1: L[b][n][m] fp32 (128x128 tile)
__global__ __launch_bounds__(256) void k_glogits(const short* __restrict__ phin_bf,
                                                 const short* __restrict__ xmd,
                                                 float* __restrict__ L) {
    __shared__ __align__(16) short lA[4096];
    __shared__ __align__(16) short lB[4096];
    int tid = threadIdx.x, b = blockIdx.z, m0 = blockIdx.x * 128;
    int w = tid >> 6, wr = w >> 1, wc = w & 1, l = tid & 63, g = l >> 4, lr = l & 15;
    f32x4 acc[4][4];
#pragma unroll
    for (int i = 0; i < 4; ++i)
#pragma unroll
        for (int j = 0; j < 4; ++j) acc[i][j] = (f32x4)(0.f);
    for (int k0 = 0; k0 < C_; k0 += 32) {
        stage32<128>(phin_bf + k0, C_, lA, tid);
        stage32<128>(xmd + ((size_t)(b * M_ + m0)) * C_ + k0, C_, lB, tid);
        __syncthreads();
        bf16x8 af[4], bf[4];
#pragma unroll
        for (int i = 0; i < 4; ++i) af[i] = fragLd(lA, wr * 64 + i * 16 + lr, g);
#pragma unroll
        for (int j = 0; j < 4; ++j) bf[j] = fragLd(lB, wc * 64 + j * 16 + lr, g);
#pragma unroll
        for (int i = 0; i < 4; ++i)
#pragma unroll
            for (int j = 0; j < 4; ++j) acc[i][j] = MFMA16(af[i], bf[j], acc[i][j]);
        __syncthreads();
    }
#pragma unroll
    for (int i = 0; i < 4; ++i)
#pragma unroll
        for (int j = 0; j < 4; ++j)
#pragma unroll
            for (int rr = 0; rr < 4; ++rr) {
                int n = wr * 64 + i * 16 + g * 4 + rr;
                int m = m0 + wc * 64 + j * 16 + lr;
                L[((size_t)b * N_ + n) * M_ + m] = acc[i][j][rr];
            }
}

// ---------------------------------------------------------------- dispatch stats
__global__ __launch_bounds__(256) void k_dstats(const float* __restrict__ L,
                                                float* __restrict__ dmax, float* __restrict__ dsum) {
    __shared__ float red[256];
    int bn = blockIdx.x;
    const float* row = L + (size_t)bn * M_;
    int t = threadIdx.x;
    float v[4];
    float mx = -3.4e38f;
#pragma unroll
    for (int i = 0; i < 4; ++i) { v[i] = row[t + 256 * i]; mx = fmaxf(mx, v[i]); }
    red[t] = mx; __syncthreads();
    for (int s = 128; s > 0; s >>= 1) { if (t < s) red[t] = fmaxf(red[t], red[t + s]); __syncthreads(); }
    float MX = red[0]; __syncthreads();
    float se = 0.f;
#pragma unroll
    for (int i = 0; i < 4; ++i) se += expf(v[i] - MX);
    red[t] = se; __syncthreads();
    for (int s = 128; s > 0; s >>= 1) { if (t < s) red[t] += red[t + s]; __syncthreads(); }
    if (t == 0) { dmax[bn] = MX; dsum[bn] = red[0]; }
}

// ---------------------------------------------------------------- combine stats
__global__ void k_cstats(const float* __restrict__ L, float* __restrict__ cmax,
                         float* __restrict__ csum) {
    int idx = blockIdx.x * 256 + threadIdx.x;
    int b = idx >> 10, m = idx & (M_ - 1);
    const float* p = L + (size_t)b * N_ * M_ + m;
    float mx = -3.4e38f;
#pragma unroll 4
    for (int n = 0; n < N_; ++n) mx = fmaxf(mx, p[(size_t)n * M_]);
    float s = 0.f;
#pragma unroll 4
    for (int n = 0; n < N_; ++n) s += expf(p[(size_t)n * M_] - mx);
    cmax[idx] = mx; csum[idx] = s;
}

// ---------------------------------------------------------------- weights: D bf16 [b][n][m], C^T bf16 [b][m][n]
__global__ __launch_bounds__(256) void k_weights(const float* __restrict__ L,
                                                 const float* __restrict__ dmax, const float* __restrict__ dsum,
                                                 const float* __restrict__ cmax, const float* __restrict__ csum,
                                                 short* __restrict__ Dbf, short* __restrict__ Ct) {
    __shared__ __align__(16) short t[64][68];
    int b = blockIdx.z, n0 = blockIdx.y * 64, m0 = blockIdx.x * 64;
    int tid = threadIdx.x;
    int col = tid & 63, rp = tid >> 6;
    float cm = cmax[b * M_ + m0 + col];
    float rcs = 1.0f / csum[b * M_ + m0 + col];
#pragma unroll 4
    for (int rr = 0; rr < 16; ++rr) {
        int row = rr * 4 + rp;
        int n = n0 + row;
        float lv = L[((size_t)b * N_ + n) * M_ + m0 + col];
        float dv = expf(lv - dmax[b * N_ + n]) * (1.0f / dsum[b * N_ + n]);
        Dbf[((size_t)b * N_ + n) * M_ + m0 + col] = f2b(dv);
        t[row][col] = f2b(expf(lv - cm) * rcs);
    }
    __syncthreads();
    int cq = (tid & 15) * 4, rp2 = tid >> 4;
#pragma unroll
    for (int p = 0; p < 4; ++p) {
        int m = m0 + p * 16 + rp2;
        short4 v;
        v.x = t[cq + 0][p * 16 + rp2]; v.y = t[cq + 1][p * 16 + rp2];
        v.z = t[cq + 2][p * 16 + rp2]; v.w = t[cq + 3][p * 16 + rp2];
        *reinterpret_cast<short4*>(Ct + ((size_t)b * M_ + m) * N_ + n0 + cq) = v;
    }
}

// ---------------------------------------------------------------- G2: xs_bf[b][n][d] (64x128 tile, K=M)
__global__ __launch_bounds__(256) void k_gxs(const short* __restrict__ Dbf,
                                             const short* __restrict__ xdm,
                                             short* __restrict__ xs_bf) {
    __shared__ __align__(16) short lA[2048];
    __shared__ __align__(16) short lB[4096];
    int tid = threadIdx.x, b = blockIdx.z, n0 = blockIdx.y * 64, d0 = blockIdx.x * 128;
    int w = tid >> 6, l = tid & 63, g = l >> 4, lr = l & 15;
    f32x4 acc[4][2];
#pragma unroll
    for (int i = 0; i < 4; ++i)
#pragma unroll
        for (int j = 0; j < 2; ++j) acc[i][j] = (f32x4)(0.f);
    for (int k0 = 0; k0 < M_; k0 += 32) {
        stage32<64>(Dbf + ((size_t)(b * N_ + n0)) * M_ + k0, M_, lA, tid);
        stage32<128>(xdm + ((size_t)(b * C_ + d0)) * M_ + k0, M_, lB, tid);
        __syncthreads();
        bf16x8 af[4], bf[2];
#pragma unroll
        for (int i = 0; i < 4; ++i) af[i] = fragLd(lA, i * 16 + lr, g);
#pragma unroll
        for (int j = 0; j < 2; ++j) bf[j] = fragLd(lB, w * 32 + j * 16 + lr, g);
#pragma unroll
        for (int i = 0; i < 4; ++i)
#pragma unroll
            for (int j = 0; j < 2; ++j) acc[i][j] = MFMA16(af[i], bf[j], acc[i][j]);
        __syncthreads();
    }
#pragma unroll
    for (int i = 0; i < 4; ++i)
#pragma unroll
        for (int j = 0; j < 2; ++j)
#pragma unroll
            for (int rr = 0; rr < 4; ++rr) {
                int n = n0 + i * 16 + g * 4 + rr;
                int d = d0 + w * 32 + j * 16 + lr;
                xs_bf[((size_t)b * N_ + n) * C_ + d] = f2b(acc[i][j][rr]);
            }
}

// ---------------------------------------------------------------- G3: ys_bf[b][n][o]; B-side reg-staged fp32->bf16
__global__ __launch_bounds__(256) void k_gys(const short* __restrict__ xs_bf,
                                             const float* __restrict__ w_exp,
                                             const float* __restrict__ b_exp,
                                             short* __restrict__ ys_bf) {
    __shared__ __align__(16) short lA[2048];
    __shared__ __align__(16) short lB[4096];
    int tid = threadIdx.x, n = blockIdx.y, o0 = blockIdx.x * 128;
    int w = tid >> 6, l = tid & 63, g = l >> 4, lr = l & 15;
    f32x4 acc[4][2];
#pragma unroll
    for (int i = 0; i < 4; ++i)
#pragma unroll
        for (int j = 0; j < 2; ++j) acc[i][j] = (f32x4)(0.f);
    for (int k0 = 0; k0 < C_; k0 += 32) {
        stage32<64>(xs_bf + (size_t)n * C_ + k0, (size_t)N_ * C_, lA, tid);
        // B tile 128(o) x 32(k): reg-stage w_exp fp32 -> bf16, swizzled ds_write
#pragma unroll
        for (int h = 0; h < 2; ++h) {
            int cc = h * 256 + tid;
            int row = cc >> 2, kq = cc & 3;
            const float* src = w_exp + ((size_t)n * C_ + o0 + row) * C_ + k0 + kq * 8;
            float4 a = *reinterpret_cast<const float4*>(src);
            float4 bq = *reinterpret_cast<const float4*>(src + 4);
            bf16x8 r;
            r[0] = f2b(a.x); r[1] = f2b(a.y); r[2] = f2b(a.z); r[3] = f2b(a.w);
            r[4] = f2b(bq.x); r[5] = f2b(bq.y); r[6] = f2b(bq.z); r[7] = f2b(bq.w);
            int slot = kq ^ ((row >> 1) & 3);
            *reinterpret_cast<bf16x8*>(lB + row * 32 + slot * 8) = r;
        }
        __syncthreads();
        bf16x8 af[4], bf[2];
#pragma unroll
        for (int i = 0; i < 4; ++i) af[i] = fragLd(lA, i * 16 + lr, g);
#pragma unroll
        for (int j = 0; j < 2; ++j) bf[j] = fragLd(lB, w * 32 + j * 16 + lr, g);
#pragma unroll
        for (int i = 0; i < 4; ++i)
#pragma unroll
            for (int j = 0; j < 2; ++j) acc[i][j] = MFMA16(af[i], bf[j], acc[i][j]);
        __syncthreads();
    }
#pragma unroll
    for (int i = 0; i < 4; ++i)
#pragma unroll
        for (int j = 0; j < 2; ++j)
#pragma unroll
            for (int rr = 0; rr < 4; ++rr) {
                int bb = i * 16 + g * 4 + rr;
                int o = o0 + w * 32 + j * 16 + lr;
                float v = acc[i][j][rr] + b_exp[n * C_ + o];
                ys_bf[((size_t)bb * N_ + n) * C_ + o] = f2b(v);
            }
}

// ---------------------------------------------------------------- G4: out[b][d][m] fp32 (128x128 tile, K=N)
__global__ __launch_bounds__(256) void k_gy(const short* __restrict__ ysT,
                                            const short* __restrict__ Ct,
                                            float* __restrict__ out) {
    __shared__ __align__(16) short lA[4096];
    __shared__ __align__(16) short lB[4096];
    int tid = threadIdx.x, b = blockIdx.z, d0 = blockIdx.y * 128, m0 = blockIdx.x * 128;
    int w = tid >> 6, wr = w >> 1, wc = w & 1, l = tid & 63, g = l >> 4, lr = l & 15;
    f32x4 acc[4][4];
#pragma unroll
    for (int i = 0; i < 4; ++i)
#pragma unroll
        for (int j = 0; j < 4; ++j) acc[i][j] = (f32x4)(0.f);
    for (int k0 = 0; k0 < N_; k0 += 32) {
        stage32<128>(ysT + ((size_t)(b * C_ + d0)) * N_ + k0, N_, lA, tid);
        stage32<128>(Ct + ((size_t)(b * M_ + m0)) * N_ + k0, N_, lB, tid);
        __syncthreads();
        bf16x8 af[4], bf[4];
#pragma unroll
        for (int i = 0; i < 4; ++i) af[i] = fragLd(lA, wr * 64 + i * 16 + lr, g);
#pragma unroll
        for (int j = 0; j < 4; ++j) bf[j] = fragLd(lB, wc * 64 + j * 16 + lr, g);
#pragma unroll
        for (int i = 0; i < 4; ++i)
#pragma unroll
            for (int j = 0; j < 4; ++j) acc[i][j] = MFMA16(af[i], bf[j], acc[i][j]);
        __syncthreads();
    }
#pragma unroll
    for (int i = 0; i < 4; ++i)
#pragma unroll
        for (int j = 0; j < 4; ++j)
#pragma unroll
            for (int rr = 0; rr < 4; ++rr) {
                int d = d0 + wr * 64 + i * 16 + g * 4 + rr;
                int m = m0 + wc * 64 + j * 16 + lr;
                out[((size_t)b * C_ + d) * M_ + m] = acc[i][j][rr];
            }
}

extern "C" void kernel_launch(void* const* d_in, const int* in_sizes, int n_in,
                              void* d_out, int out_size, void* d_ws, size_t ws_size,
                              hipStream_t stream) {
    const float* x     = (const float*)d_in[0];
    const float* phi   = (const float*)d_in[1];
    const float* scale = (const float*)d_in[2];
    const float* w_exp = (const float*)d_in[3];
    const float* b_exp = (const float*)d_in[4];
    float* out = (float*)d_out;

    char* w = (char*)d_ws;
    float* L     = (float*)(w + 0);                 // 33,554,432 B
    float* dmax  = (float*)(w + 33554432);          // 32,768
    float* dsum  = (float*)(w + 33587200);          // 32,768
    float* cmax  = (float*)(w + 33619968);          // 262,144
    float* csum  = (float*)(w + 33882112);          // 262,144
    short* phin  = (short*)(w + 34144256);          // 98,304
    short* xdm   = (short*)(w + 34242560);          // 50,331,648  xn bf16 [b][d][m]
    short* xmd   = (short*)(w + 84574208);          // 50,331,648  xn bf16 [b][m][d] (dead after G1)
    short* Dbf   = (short*)(w + 134905856);         // 16,777,216
    short* Ct    = (short*)(w + 151683072);         // 16,777,216  (end: 168,460,288)
    // alias into xmd region (xmd dead after k_glogits; these written after):
    short* xs_bf = xmd;                             // 6,291,456
    short* ys_bf = xmd + 3145728;                   // 6,291,456
    short* ysT   = xmd + 6291456;                   // 6,291,456

    if (ws_size < 168460288) return;  // clean failure instead of OOB

    k_phin<<<dim3(128), dim3(64), 0, stream>>>(phi, scale, phin);
    k_xnt<<<dim3(16, 64), dim3(256), 0, stream>>>(x, xdm, xmd);
    k_glogits<<<dim3(8, 1, 64), dim3(256), 0, stream>>>(phin, xmd, L);
    k_dstats<<<dim3(8192), dim3(256), 0, stream>>>(L, dmax, dsum);
    k_cstats<<<dim3(256), dim3(256), 0, stream>>>(L, cmax, csum);
    k_weights<<<dim3(16, 2, 64), dim3(256), 0, stream>>>(L, dmax, dsum, cmax, csum, Dbf, Ct);
    k_gxs<<<dim3(3, 2, 64), dim3(256), 0, stream>>>(Dbf, xdm, xs_bf);
    k_gys<<<dim3(3, 128), dim3(256), 0, stream>>>(xs_bf, w_exp, b_exp, ys_bf);
    k_tr<<<dim3(6, 2, 64), dim3(256), 0, stream>>>(ys_bf, ysT, N_, C_);
    k_gy<<<dim3(8, 3, 64), dim3(256), 0, stream>>>(ysT, Ct, out);
}